// Round 1
// baseline (1122.635 us; speedup 1.0000x reference)
//
#include <hip/hip_runtime.h>

// Scaled dot-product attention, fp32, with materialized attn output.
// B=64, TQ=TK=1024, DK=DV=64.
// One 256-thread workgroup handles 16 query rows of one batch.
// LDS: q tile (16x64, stride 68), K/V tile buffer (aliased: K transposed
// [64][132] / V [128][68]), p tile [16][132]. ~47.6 KB -> 3 WG/CU.

#define B_   64
#define TQ_  1024
#define TK_  1024
#define DD   64
#define BQ   16
#define BK   128
#define KSTR 132
#define VSTR 68
#define QSTR 68
#define PSTR 132

__global__ __launch_bounds__(256, 2) void attn_fp32_kernel(
    const float* __restrict__ qg,
    const float* __restrict__ kg,
    const float* __restrict__ vg,
    const int*   __restrict__ maskg,
    float* __restrict__ outg,   // [B][TQ][DD]
    float* __restrict__ attng)  // [B][TQ][TK]
{
    __shared__ float q_lds[BQ * QSTR];       // 1088 floats
    __shared__ float kv_lds[BK * VSTR];      // 8704 floats (>= 64*132 = 8448)
    __shared__ float p_lds[BQ * PSTR];       // 2112 floats

    const int t     = threadIdx.x;
    const int q_loc = t >> 4;    // 0..15  (query row within tile)
    const int tx    = t & 15;    // 0..15  (column-group thread)
    const int b     = blockIdx.y;
    const int q0    = blockIdx.x * BQ;
    const int qgidx = q0 + q_loc;

    const float* qb = qg + ((size_t)b * TQ_ + q0) * DD;
    const float* kb = kg + (size_t)b * TK_ * DD;
    const float* vb = vg + (size_t)b * TK_ * DD;
    const int* mrow   = maskg + ((size_t)b * TQ_ + qgidx) * (size_t)TK_;
    float* attn_row   = attng + ((size_t)b * TQ_ + qgidx) * (size_t)TK_;
    float* out_row    = outg  + ((size_t)b * TQ_ + qgidx) * DD;

    // ---- stage q tile (one float4 per thread) ----
    {
        const int r  = t >> 4;
        const int d4 = t & 15;
        const float4 qv = *(const float4*)(qb + r * DD + d4 * 4);
        *(float4*)(q_lds + r * QSTR + d4 * 4) = qv;
    }

    // scores: thread owns j = i*64 + tx*4 + c  (i=0..15, c=0..3)
    float s_reg[64];

    // ================= Phase 1: S = Q K^T / 8 + mask =================
    #pragma unroll
    for (int kt = 0; kt < TK_ / BK; ++kt) {
        __syncthreads();
        // stage K tile transposed: kv_lds[d*KSTR + r] = K[k0+r][d]
        #pragma unroll
        for (int s = 0; s < 8; ++s) {
            const int e4 = t + 256 * s;
            const int r  = e4 >> 4;
            const int d4 = e4 & 15;
            const float4 kv = *(const float4*)(kb + (size_t)(kt * BK + r) * DD + d4 * 4);
            kv_lds[(d4 * 4 + 0) * KSTR + r] = kv.x;
            kv_lds[(d4 * 4 + 1) * KSTR + r] = kv.y;
            kv_lds[(d4 * 4 + 2) * KSTR + r] = kv.z;
            kv_lds[(d4 * 4 + 3) * KSTR + r] = kv.w;
        }
        __syncthreads();

        float acc0[4] = {0.f, 0.f, 0.f, 0.f};
        float acc1[4] = {0.f, 0.f, 0.f, 0.f};
        #pragma unroll
        for (int d4 = 0; d4 < 16; ++d4) {
            const float4 q4 = *(const float4*)(q_lds + q_loc * QSTR + d4 * 4);
            const float qv[4] = {q4.x, q4.y, q4.z, q4.w};
            #pragma unroll
            for (int u = 0; u < 4; ++u) {
                const int d = d4 * 4 + u;
                const float4 ka = *(const float4*)(kv_lds + d * KSTR + tx * 4);
                const float4 kc = *(const float4*)(kv_lds + d * KSTR + 64 + tx * 4);
                acc0[0] = fmaf(qv[u], ka.x, acc0[0]);
                acc0[1] = fmaf(qv[u], ka.y, acc0[1]);
                acc0[2] = fmaf(qv[u], ka.z, acc0[2]);
                acc0[3] = fmaf(qv[u], ka.w, acc0[3]);
                acc1[0] = fmaf(qv[u], kc.x, acc1[0]);
                acc1[1] = fmaf(qv[u], kc.y, acc1[1]);
                acc1[2] = fmaf(qv[u], kc.z, acc1[2]);
                acc1[3] = fmaf(qv[u], kc.w, acc1[3]);
            }
        }
        // apply scale (1/sqrt(64) = 1/8) and mask
        const int4 m0 = *(const int4*)(mrow + kt * BK + tx * 4);
        const int4 m1 = *(const int4*)(mrow + kt * BK + 64 + tx * 4);
        const float sc = 0.125f;
        s_reg[(2 * kt + 0) * 4 + 0] = acc0[0] * sc + (m0.x ? 0.f : -1e9f);
        s_reg[(2 * kt + 0) * 4 + 1] = acc0[1] * sc + (m0.y ? 0.f : -1e9f);
        s_reg[(2 * kt + 0) * 4 + 2] = acc0[2] * sc + (m0.z ? 0.f : -1e9f);
        s_reg[(2 * kt + 0) * 4 + 3] = acc0[3] * sc + (m0.w ? 0.f : -1e9f);
        s_reg[(2 * kt + 1) * 4 + 0] = acc1[0] * sc + (m1.x ? 0.f : -1e9f);
        s_reg[(2 * kt + 1) * 4 + 1] = acc1[1] * sc + (m1.y ? 0.f : -1e9f);
        s_reg[(2 * kt + 1) * 4 + 2] = acc1[2] * sc + (m1.z ? 0.f : -1e9f);
        s_reg[(2 * kt + 1) * 4 + 3] = acc1[3] * sc + (m1.w ? 0.f : -1e9f);
    }

    // ================= Softmax over 1024 keys per row =================
    float mx = s_reg[0];
    #pragma unroll
    for (int i = 1; i < 64; ++i) mx = fmaxf(mx, s_reg[i]);
    #pragma unroll
    for (int off = 8; off > 0; off >>= 1) mx = fmaxf(mx, __shfl_xor(mx, off));

    float sum = 0.f;
    #pragma unroll
    for (int i = 0; i < 64; ++i) {
        s_reg[i] = __expf(s_reg[i] - mx);
        sum += s_reg[i];
    }
    #pragma unroll
    for (int off = 8; off > 0; off >>= 1) sum += __shfl_xor(sum, off);
    const float inv = 1.f / sum;
    #pragma unroll
    for (int i = 0; i < 64; ++i) s_reg[i] *= inv;

    // write attn from registers (coalesced 256B bursts per row)
    #pragma unroll
    for (int i = 0; i < 16; ++i) {
        const float4 pv = make_float4(s_reg[i * 4 + 0], s_reg[i * 4 + 1],
                                      s_reg[i * 4 + 2], s_reg[i * 4 + 3]);
        *(float4*)(attn_row + i * 64 + tx * 4) = pv;
    }

    // ================= Phase 2: out = P V =================
    float oacc[4] = {0.f, 0.f, 0.f, 0.f};
    const int d0 = tx * 4;

    #pragma unroll
    for (int kt = 0; kt < TK_ / BK; ++kt) {
        __syncthreads();
        // stage V tile: kv_lds[r*VSTR + d]
        #pragma unroll
        for (int s = 0; s < 8; ++s) {
            const int e4 = t + 256 * s;
            const int r  = e4 >> 4;
            const int d4 = e4 & 15;
            *(float4*)(kv_lds + r * VSTR + d4 * 4) =
                *(const float4*)(vb + (size_t)(kt * BK + r) * DD + d4 * 4);
        }
        // write this tile's p chunk (regs -> LDS)
        *(float4*)(p_lds + q_loc * PSTR + tx * 4) =
            make_float4(s_reg[(2 * kt + 0) * 4 + 0], s_reg[(2 * kt + 0) * 4 + 1],
                        s_reg[(2 * kt + 0) * 4 + 2], s_reg[(2 * kt + 0) * 4 + 3]);
        *(float4*)(p_lds + q_loc * PSTR + 64 + tx * 4) =
            make_float4(s_reg[(2 * kt + 1) * 4 + 0], s_reg[(2 * kt + 1) * 4 + 1],
                        s_reg[(2 * kt + 1) * 4 + 2], s_reg[(2 * kt + 1) * 4 + 3]);
        __syncthreads();

        #pragma unroll
        for (int ju = 0; ju < 32; ++ju) {
            const float4 p4 = *(const float4*)(p_lds + q_loc * PSTR + ju * 4);
            const float* vp = kv_lds + (ju * 4) * VSTR + d0;
            const float4 v0 = *(const float4*)(vp);
            const float4 v1 = *(const float4*)(vp + VSTR);
            const float4 v2 = *(const float4*)(vp + 2 * VSTR);
            const float4 v3 = *(const float4*)(vp + 3 * VSTR);
            oacc[0] = fmaf(p4.x, v0.x, oacc[0]);
            oacc[0] = fmaf(p4.y, v1.x, oacc[0]);
            oacc[0] = fmaf(p4.z, v2.x, oacc[0]);
            oacc[0] = fmaf(p4.w, v3.x, oacc[0]);
            oacc[1] = fmaf(p4.x, v0.y, oacc[1]);
            oacc[1] = fmaf(p4.y, v1.y, oacc[1]);
            oacc[1] = fmaf(p4.z, v2.y, oacc[1]);
            oacc[1] = fmaf(p4.w, v3.y, oacc[1]);
            oacc[2] = fmaf(p4.x, v0.z, oacc[2]);
            oacc[2] = fmaf(p4.y, v1.z, oacc[2]);
            oacc[2] = fmaf(p4.z, v2.z, oacc[2]);
            oacc[2] = fmaf(p4.w, v3.z, oacc[2]);
            oacc[3] = fmaf(p4.x, v0.w, oacc[3]);
            oacc[3] = fmaf(p4.y, v1.w, oacc[3]);
            oacc[3] = fmaf(p4.z, v2.w, oacc[3]);
            oacc[3] = fmaf(p4.w, v3.w, oacc[3]);
        }
    }

    *(float4*)(out_row + d0) = make_float4(oacc[0], oacc[1], oacc[2], oacc[3]);
}

extern "C" void kernel_launch(void* const* d_in, const int* in_sizes, int n_in,
                              void* d_out, int out_size, void* d_ws, size_t ws_size,
                              hipStream_t stream) {
    const float* q    = (const float*)d_in[0];
    const float* k    = (const float*)d_in[1];
    const float* v    = (const float*)d_in[2];
    const int*   mask = (const int*)d_in[3];

    float* out  = (float*)d_out;                       // [64][1024][64]
    float* attn = out + (size_t)B_ * TQ_ * DD;         // [64][1024][1024]

    dim3 grid(TQ_ / BQ, B_);
    attn_fp32_kernel<<<grid, 256, 0, stream>>>(q, k, v, mask, out, attn);
}

// Round 2
// 628.824 us; speedup vs baseline: 1.7853x; 1.7853x over previous
//
#include <hip/hip_runtime.h>
#include <hip/hip_bf16.h>

// bf16-MFMA scaled dot-product attention with materialized attn.
// B=64, TQ=TK=1024, DK=DV=64.
// WG = 256 thr = 4 waves; 16 queries per WG; wave w owns keys [w*256, w*256+256).
// S[16x256] per wave in 64 VGPRs/lane (MFMA C-layout). Softmax stats combined
// across waves via LDS. P -> LDS (bf16) for the PV MFMA A-operand; V staged
// transposed per-wave in LDS for ds_read_b128 B-frags.

#define B_   64
#define TQ_  1024
#define TK_  1024
#define DD   64

typedef short short8 __attribute__((ext_vector_type(8)));
typedef float f32x4 __attribute__((ext_vector_type(4)));

#define PSTR 264            // shorts per P row: 16B-aligned rows, 2-way banks (free)
#define VSTR 40             // shorts per Vt row (32-key chunks): 16B-aligned rows
#define PWAVE (16 * PSTR)   // 4224 shorts = 8448 B per wave
#define VWAVE (64 * VSTR)   // 2560 shorts = 5120 B per wave
// total LDS: 4*(8448+5120) = 54272 B -> 3 WG/CU

__device__ __forceinline__ unsigned cvt2(float a, float b) {
    __hip_bfloat162 h = __float22bfloat162_rn(make_float2(a, b));
    unsigned u; __builtin_memcpy(&u, &h, 4); return u;
}
__device__ __forceinline__ short cvt1(float a) {
    __hip_bfloat16 h = __float2bfloat16(a);
    short s; __builtin_memcpy(&s, &h, 2); return s;
}

union Frag { short8 s; unsigned u[4]; };

__global__ __launch_bounds__(256, 3) void attn_mfma_kernel(
    const float* __restrict__ qg, const float* __restrict__ kg,
    const float* __restrict__ vg, const int* __restrict__ maskg,
    float* __restrict__ outg, float* __restrict__ attng)
{
    __shared__ __align__(16) short p_lds[4 * PWAVE];
    __shared__ __align__(16) short vt_lds[4 * VWAVE];

    const int t    = threadIdx.x;
    const int wave = t >> 6, lane = t & 63;
    const int quad = lane >> 4, n16 = lane & 15;
    const int b    = blockIdx.y;
    const int q0   = blockIdx.x * 16;
    const int kbase = wave * 256;

    short* pw = p_lds + wave * PWAVE;
    short* vw = vt_lds + wave * VWAVE;
    float* redmax = (float*)vt_lds;        // [4][16], aliased into vt (phase C only)
    float* redsum = (float*)vt_lds + 64;   // [4][16]

    // ---- Q A-frags: lane n16 holds Q[q0+n16][f*32 + quad*8 + j] ----
    Frag aq[2];
    {
        const float* qp = qg + ((size_t)(b * TQ_ + q0 + n16)) * DD + quad * 8;
        #pragma unroll
        for (int f = 0; f < 2; ++f) {
            float4 x = *(const float4*)(qp + f * 32);
            float4 y = *(const float4*)(qp + f * 32 + 4);
            aq[f].u[0] = cvt2(x.x, x.y); aq[f].u[1] = cvt2(x.z, x.w);
            aq[f].u[2] = cvt2(y.x, y.y); aq[f].u[3] = cvt2(y.z, y.w);
        }
    }

    float s_reg[64];   // 16 key-tiles x 4 regs; s_reg[kt*4+r]: row quad*4+r, key kt*16+n16

    // ================= S = Q K^T * 0.125 + mask =================
    const float* kbp = kg + (size_t)b * TK_ * DD;
    const int*   mbp = maskg + ((size_t)(b * TQ_ + q0 + quad * 4)) * TK_ + kbase + n16;
    #pragma unroll
    for (int kt = 0; kt < 16; ++kt) {
        const int key0 = kbase + kt * 16;
        const float* kp = kbp + (size_t)(key0 + n16) * DD + quad * 8;
        Frag bk[2];
        #pragma unroll
        for (int f = 0; f < 2; ++f) {
            float4 x = *(const float4*)(kp + f * 32);
            float4 y = *(const float4*)(kp + f * 32 + 4);
            bk[f].u[0] = cvt2(x.x, x.y); bk[f].u[1] = cvt2(x.z, x.w);
            bk[f].u[2] = cvt2(y.x, y.y); bk[f].u[3] = cvt2(y.z, y.w);
        }
        f32x4 acc = {0.f, 0.f, 0.f, 0.f};
        acc = __builtin_amdgcn_mfma_f32_16x16x32_bf16(aq[0].s, bk[0].s, acc, 0, 0, 0);
        acc = __builtin_amdgcn_mfma_f32_16x16x32_bf16(aq[1].s, bk[1].s, acc, 0, 0, 0);
        #pragma unroll
        for (int r = 0; r < 4; ++r) {
            const int m = mbp[(size_t)r * TK_ + kt * 16];
            s_reg[kt * 4 + r] = acc[r] * 0.125f + (m ? 0.f : -1e9f);
        }
    }

    // ================= softmax (cross-wave via LDS) =================
    float rmax[4];
    #pragma unroll
    for (int r = 0; r < 4; ++r) {
        float m = s_reg[r];
        #pragma unroll
        for (int kt = 1; kt < 16; ++kt) m = fmaxf(m, s_reg[kt * 4 + r]);
        #pragma unroll
        for (int off = 8; off > 0; off >>= 1) m = fmaxf(m, __shfl_xor(m, off));
        rmax[r] = m;
    }
    if (n16 == 0) {
        #pragma unroll
        for (int r = 0; r < 4; ++r) redmax[wave * 16 + quad * 4 + r] = rmax[r];
    }
    __syncthreads();
    float gmax[4];
    #pragma unroll
    for (int r = 0; r < 4; ++r) {
        const int row = quad * 4 + r;
        gmax[r] = fmaxf(fmaxf(redmax[row], redmax[16 + row]),
                        fmaxf(redmax[32 + row], redmax[48 + row]));
    }
    float lsum[4] = {0.f, 0.f, 0.f, 0.f};
    #pragma unroll
    for (int kt = 0; kt < 16; ++kt) {
        #pragma unroll
        for (int r = 0; r < 4; ++r) {
            const float p = __expf(s_reg[kt * 4 + r] - gmax[r]);
            s_reg[kt * 4 + r] = p;
            lsum[r] += p;
        }
    }
    #pragma unroll
    for (int r = 0; r < 4; ++r) {
        #pragma unroll
        for (int off = 8; off > 0; off >>= 1) lsum[r] += __shfl_xor(lsum[r], off);
    }
    if (n16 == 0) {
        #pragma unroll
        for (int r = 0; r < 4; ++r) redsum[wave * 16 + quad * 4 + r] = lsum[r];
    }
    __syncthreads();
    float inv[4];
    #pragma unroll
    for (int r = 0; r < 4; ++r) {
        const int row = quad * 4 + r;
        inv[r] = 1.f / (redsum[row] + redsum[16 + row] + redsum[32 + row] + redsum[48 + row]);
    }
    __syncthreads();   // red region (aliased in vt_lds) free before Vt staging

    // ---- normalize; write attn (fp32) and P (bf16 -> LDS) ----
    float* abp = attng + ((size_t)(b * TQ_ + q0 + quad * 4)) * TK_ + kbase + n16;
    #pragma unroll
    for (int kt = 0; kt < 16; ++kt) {
        #pragma unroll
        for (int r = 0; r < 4; ++r) {
            const float pv = s_reg[kt * 4 + r] * inv[r];
            abp[(size_t)r * TK_ + kt * 16] = pv;
            pw[(quad * 4 + r) * PSTR + kt * 16 + n16] = cvt1(pv);
        }
    }

    // ================= O = P V =================
    f32x4 oacc[4];
    #pragma unroll
    for (int dg = 0; dg < 4; ++dg) oacc[dg] = (f32x4){0.f, 0.f, 0.f, 0.f};

    const float* vbp = vg + (size_t)b * TK_ * DD;
    #pragma unroll 1
    for (int c = 0; c < 8; ++c) {
        const int ck0 = kbase + c * 32;
        // stage Vt[d=lane][k-pairs] (wave-private, transposed, bf16)
        #pragma unroll
        for (int i = 0; i < 16; ++i) {
            const float v0 = vbp[(size_t)(ck0 + 2 * i) * DD + lane];
            const float v1 = vbp[(size_t)(ck0 + 2 * i + 1) * DD + lane];
            *(unsigned*)(vw + lane * VSTR + 2 * i) = cvt2(v0, v1);
        }
        Frag pf;
        pf.s = *(const short8*)(pw + n16 * PSTR + c * 32 + quad * 8);
        #pragma unroll
        for (int dg = 0; dg < 4; ++dg) {
            Frag vf;
            vf.s = *(const short8*)(vw + (dg * 16 + n16) * VSTR + quad * 8);
            oacc[dg] = __builtin_amdgcn_mfma_f32_16x16x32_bf16(pf.s, vf.s, oacc[dg], 0, 0, 0);
        }
    }

    // ---- cross-wave O reduction (stage into own p region: 16x68 fp32) ----
    float* ow = (float*)pw;
    #pragma unroll
    for (int dg = 0; dg < 4; ++dg) {
        #pragma unroll
        for (int r = 0; r < 4; ++r)
            ow[(quad * 4 + r) * 68 + dg * 16 + n16] = oacc[dg][r];
    }
    __syncthreads();
    {
        const int row = t >> 4;
        const int col = (t & 15) * 4;
        const float* p0 = (const float*)p_lds;
        float4 o = make_float4(0.f, 0.f, 0.f, 0.f);
        #pragma unroll
        for (int w = 0; w < 4; ++w) {
            const float4 x = *(const float4*)(p0 + w * (PWAVE / 2) + row * 68 + col);
            o.x += x.x; o.y += x.y; o.z += x.z; o.w += x.w;
        }
        *(float4*)(outg + ((size_t)(b * TQ_ + q0 + row)) * DD + col) = o;
    }
}

extern "C" void kernel_launch(void* const* d_in, const int* in_sizes, int n_in,
                              void* d_out, int out_size, void* d_ws, size_t ws_size,
                              hipStream_t stream) {
    const float* q    = (const float*)d_in[0];
    const float* k    = (const float*)d_in[1];
    const float* v    = (const float*)d_in[2];
    const int*   mask = (const int*)d_in[3];

    float* out  = (float*)d_out;                   // [64][1024][64]
    float* attn = out + (size_t)B_ * TQ_ * DD;     // [64][1024][1024]

    dim3 grid(TQ_ / 16, B_);
    attn_mfma_kernel<<<grid, 256, 0, stream>>>(q, k, v, mask, out, attn);
}